// Round 1
// baseline (73.084 us; speedup 1.0000x reference)
//
#include <hip/hip_runtime.h>

// Quantum multi-headed attention, algebraically reduced.
//
// Key reductions (see derivation):
//  - measure() reads only Re(diag(rho)); CNOT-network conjugation permutes the
//    diagonal, so cal_query_key reduces to per-qubit Z expectations:
//      score[t]    = (Zq[t]*Sk + 1)/2          (t = 0..2, q-register qubits)
//      score[3+t]  = (Zq[t]*Zk[t] + 1)/2       (k-register qubits)
//    with Z[t] = sum_a sign(bit t of a) * |psi_a|^2, Sk = ||psi_k||^2.
//  - cal_output's ptrace of the permuted kron gives, on the diagonal,
//      diag(attn)[p] = A0[p,p] * tr(A1) * tr(A2) * tr(A3)
//    and tr(A_j) = tr(encoding_j) = (||x||/(||x||+1e-12))^2  (unitary-invariant).
//  - A0 = U(phi_i) (Uv x_v0)(Uv x_v0)^H U(phi_i)^H, so diag(A0)[p] = |psi_p|^2
//    with psi = (u ox u ox u) Uv x_v0, u = rz(phi) ry(phi/2) rx(phi/2),
//    phi_i = (pi/6) * ( Sk*sum_t Zq_i[t] + sum_t Zq_i[t]*Zk_0[t] ).
//
// Output: out[i*3+q] = ( sum_p sign(q,p) |psi_p|^2 * r + 1 ) / 2, r = prod traces.

struct cplx { float re, im; };
__device__ __forceinline__ cplx cmul(cplx a, cplx b){ return {a.re*b.re - a.im*b.im, a.re*b.im + a.im*b.re}; }
__device__ __forceinline__ cplx cadd(cplx a, cplx b){ return {a.re+b.re, a.im+b.im}; }

// m = rz(pz) @ ry(py) @ rx(px)
__device__ void build_gate(float px, float py, float pz, cplx m[2][2]){
    float cx = cosf(0.5f*px), sx = sinf(0.5f*px);
    float cy = cosf(0.5f*py), sy = sinf(0.5f*py);
    float cz = cosf(0.5f*pz), sz = sinf(0.5f*pz);
    cplx rxm[2][2] = {{{cx,0.f},{0.f,-sx}},{{0.f,-sx},{cx,0.f}}};
    cplx rym[2][2] = {{{cy,0.f},{-sy,0.f}},{{sy,0.f},{cy,0.f}}};
    cplx t[2][2];
    #pragma unroll
    for(int r=0;r<2;r++)
        #pragma unroll
        for(int c=0;c<2;c++)
            t[r][c] = cadd(cmul(rym[r][0],rxm[0][c]), cmul(rym[r][1],rxm[1][c]));
    cplx e0 = {cz,-sz}, e1 = {cz, sz};
    m[0][0]=cmul(e0,t[0][0]); m[0][1]=cmul(e0,t[0][1]);
    m[1][0]=cmul(e1,t[1][0]); m[1][1]=cmul(e1,t[1][1]);
}

// apply 2x2 gate m to qubit q (qubit 0 = MSB of 3-bit index) of 8-vector v
__device__ void apply_gate(cplx v[8], const cplx m[2][2], int q){
    int bit = 1 << (2 - q);
    #pragma unroll
    for (int a = 0; a < 8; ++a){
        if (a & bit) continue;
        cplx v0 = v[a], v1 = v[a|bit];
        v[a]     = cadd(cmul(m[0][0], v0), cmul(m[0][1], v1));
        v[a|bit] = cadd(cmul(m[1][0], v0), cmul(m[1][1], v1));
    }
}

// encoding state: |x| / (||x||_2 + 1e-12) as a complex 8-vector
__device__ void enc_state(const float* __restrict__ row, cplx v[8]){
    float n2 = 0.f;
    float x[8];
    #pragma unroll
    for (int j=0;j<8;j++){ x[j] = fabsf(row[j]); n2 += x[j]*x[j]; }
    float n = sqrtf(n2) + 1e-12f;
    #pragma unroll
    for (int j=0;j<8;j++){ v[j].re = x[j]/n; v[j].im = 0.f; }
}

__device__ __forceinline__ float prob(cplx a){ return a.re*a.re + a.im*a.im; }

__global__ void __launch_bounds__(64)
qattn_kernel(const float* __restrict__ Q, const float* __restrict__ K,
             const float* __restrict__ V, const float* __restrict__ wq,
             const float* __restrict__ wk, const float* __restrict__ wv,
             float* __restrict__ out)
{
    const int i = threadIdx.x;      // output row (token)
    if (i >= 4) return;
    const float WM = 0.632455532033675866f;   // sqrt(2/5)
    const float PI = 3.14159265358979323846f;

    // per-qubit circuit gates
    cplx mq[3][2][2], mk[3][2][2], mv[3][2][2];
    #pragma unroll
    for (int t=0;t<3;t++){
        build_gate(wq[3*t]*WM, wq[3*t+1]*WM, wq[3*t+2]*WM, mq[t]);
        build_gate(wk[3*t]*WM, wk[3*t+1]*WM, wk[3*t+2]*WM, mk[t]);
        build_gate(wv[3*t]*WM, wv[3*t+1]*WM, wv[3*t+2]*WM, mv[t]);
    }

    // psi_q = Uq x_q[i];  Zq[t]
    cplx pq[8]; enc_state(&Q[i*8], pq);
    apply_gate(pq, mq[0], 0); apply_gate(pq, mq[1], 1); apply_gate(pq, mq[2], 2);
    float Zq[3];
    #pragma unroll
    for (int t=0;t<3;t++){
        int bit = 1 << (2 - t); float s = 0.f;
        #pragma unroll
        for (int a=0;a<8;a++){ float p = prob(pq[a]); s += (a & bit) ? -p : p; }
        Zq[t] = s;
    }

    // psi_k = Uk x_k[0];  Zk[t], Sk
    cplx pk[8]; enc_state(&K[0], pk);
    apply_gate(pk, mk[0], 0); apply_gate(pk, mk[1], 1); apply_gate(pk, mk[2], 2);
    float Zk[3], Sk = 0.f;
    #pragma unroll
    for (int a=0;a<8;a++) Sk += prob(pk[a]);
    #pragma unroll
    for (int t=0;t<3;t++){
        int bit = 1 << (2 - t); float s = 0.f;
        #pragma unroll
        for (int a=0;a<8;a++){ float p = prob(pk[a]); s += (a & bit) ? -p : p; }
        Zk[t] = s;
    }

    // phi_i = (pi/6) * sum of the 6 raw (pre-affine) score components
    float sx = Sk*(Zq[0]+Zq[1]+Zq[2]) + Zq[0]*Zk[0] + Zq[1]*Zk[1] + Zq[2]*Zk[2];
    float phi = PI * sx / 6.f;

    // psi = (u ox u ox u) Uv x_v[0],  u = rz(phi) ry(phi/2) rx(phi/2)
    cplx pv[8]; enc_state(&V[0], pv);
    apply_gate(pv, mv[0], 0); apply_gate(pv, mv[1], 1); apply_gate(pv, mv[2], 2);
    cplx u[2][2]; build_gate(0.5f*phi, 0.5f*phi, phi, u);
    apply_gate(pv, u, 0); apply_gate(pv, u, 1); apply_gate(pv, u, 2);

    // r = tr(A1)*tr(A2)*tr(A3) = prod_j (||v_j||/(||v_j||+1e-12))^2  (~1.0)
    float r = 1.f;
    #pragma unroll
    for (int j=1;j<4;j++){
        float n2 = 0.f;
        #pragma unroll
        for (int c=0;c<8;c++){ float a = fabsf(V[j*8+c]); n2 += a*a; }
        float n = sqrtf(n2);
        float f = n / (n + 1e-12f);
        r *= f*f;
    }

    // out[i][t] = ( sum_p sign * |psi_p|^2 * r + 1 ) / 2
    #pragma unroll
    for (int t=0;t<3;t++){
        int bit = 1 << (2 - t); float s = 0.f;
        #pragma unroll
        for (int p=0;p<8;p++){ float pr = prob(pv[p]); s += (p & bit) ? -pr : pr; }
        out[i*3 + t] = 0.5f * (s * r + 1.f);
    }
}

extern "C" void kernel_launch(void* const* d_in, const int* in_sizes, int n_in,
                              void* d_out, int out_size, void* d_ws, size_t ws_size,
                              hipStream_t stream) {
    const float* Q  = (const float*)d_in[0];
    const float* K  = (const float*)d_in[1];
    const float* V  = (const float*)d_in[2];
    const float* wq = (const float*)d_in[3];
    const float* wk = (const float*)d_in[4];
    const float* wv = (const float*)d_in[5];
    float* out = (float*)d_out;
    qattn_kernel<<<1, 64, 0, stream>>>(Q, K, V, wq, wk, wv, out);
}